// Round 1
// baseline (251.964 us; speedup 1.0000x reference)
//
#include <hip/hip_runtime.h>

#define NNODE  18
#define ROWF2  9            // float2 per adj row
#define ADJ_F  324          // floats per batch (18*18)
#define ADJ_F2 162          // float2 per batch
#define TILE   62           // batches per block (62*326*4 = 80,848 B LDS -> 2 blocks/CU)
#define STRIDE 326          // padded LDS floats per batch (324 -> 8-way conflicts; 326 -> ~4-way)

__global__ __launch_bounds__(64, 1) void gcnn_fused(
    const float* __restrict__ nf,      // [B,18]
    const float* __restrict__ adj,     // [B,18,18]
    const float* __restrict__ proj_w,  // [1]
    const float* __restrict__ proj_b,  // [1]
    const float* __restrict__ w1, const float* __restrict__ b1,   // [10,18],[10]
    const float* __restrict__ w2, const float* __restrict__ b2,   // [8,10],[8]
    const float* __restrict__ w3, const float* __restrict__ b3,   // [2,8],[2]
    float* __restrict__ out,           // [B,2]
    int B)
{
    extern __shared__ float lds[];     // TILE * STRIDE floats
    const int lane = threadIdx.x;      // block = 1 wave
    const int b0   = blockIdx.x * TILE;
    const int nb   = min(TILE, B - b0);
    const int nF2  = nb * ADJ_F2;

    // ---- Stage adj tile: contiguous coalesced float2 loads, padded LDS writes ----
    const float2* __restrict__ gsrc = (const float2*)(adj + (size_t)b0 * ADJ_F);
    #pragma unroll 8
    for (int r = 0; r < (TILE * ADJ_F2 + 63) / 64; ++r) {   // 157 rounds
        unsigned idx2 = (unsigned)(r * 64 + lane);
        if ((int)idx2 < nF2) {
            float2 v = gsrc[idx2];
            unsigned batch = idx2 / ADJ_F2;                 // magic-div by const
            unsigned off2  = idx2 - batch * ADJ_F2;
            *(float2*)&lds[batch * STRIDE + off2 * 2] = v;  // ds_write_b64, 8-aligned
        }
    }
    __syncthreads();   // 1-wave block: cheap; drains lgkm before cross-lane LDS reads

    // ---- Per-thread compute: one batch element, both GCN layers from the SAME tile ----
    const int b = b0 + lane;
    if (lane < TILE && b < B) {
        const float pw = proj_w[0], pb = proj_b[0];
        const float* __restrict__ my = &lds[lane * STRIDE];

        // node features (divergent but tiny: 72 B/thread)
        float x[NNODE];
        const float2* __restrict__ nfp = (const float2*)(nf + (size_t)b * NNODE);
        #pragma unroll
        for (int j = 0; j < ROWF2; ++j) { float2 v = nfp[j]; x[2*j] = v.x; x[2*j+1] = v.y; }

        // Layer 1: deg (row-sum) + matvec in one sweep.
        // h = relu( (A(w*x + pb*1))/deg ) = relu( w*(A x)/deg + pb )  since A*1 = deg
        float invd[NNODE], h[NNODE];
        #pragma unroll
        for (int n = 0; n < NNODE; ++n) {
            const float2* __restrict__ row = (const float2*)(my + n * NNODE);
            float d = 0.f, s = 0.f;
            #pragma unroll
            for (int m = 0; m < ROWF2; ++m) {
                float2 a = row[m];              // ds_read_b64
                d += a.x + a.y;
                s += a.x * x[2*m] + a.y * x[2*m+1];
            }
            float inv = 1.0f / d;
            invd[n] = inv;
            h[n] = fmaxf(0.f, pw * s * inv + pb);
        }

        // Layer 2: re-read rows from LDS (resident), reuse 1/deg
        float y[NNODE];
        #pragma unroll
        for (int n = 0; n < NNODE; ++n) {
            const float2* __restrict__ row = (const float2*)(my + n * NNODE);
            float s = 0.f;
            #pragma unroll
            for (int m = 0; m < ROWF2; ++m) {
                float2 a = row[m];
                s += a.x * h[2*m] + a.y * h[2*m+1];
            }
            float v = fmaxf(0.f, pw * s * invd[n] + pb);
            y[n] = (v != v) ? 0.f : v;          // NaN scrub (matches reference)
        }

        // MLP head (weights: uniform-address global loads -> broadcast, cache-served)
        float z1[10];
        #pragma unroll
        for (int k = 0; k < 10; ++k) {
            float s = b1[k];
            #pragma unroll
            for (int j = 0; j < NNODE; ++j) s += w1[k*NNODE + j] * y[j];
            z1[k] = fmaxf(0.f, s);
        }
        float z2[8];
        #pragma unroll
        for (int k = 0; k < 8; ++k) {
            float s = b2[k];
            #pragma unroll
            for (int j = 0; j < 10; ++j) s += w2[k*10 + j] * z1[j];
            z2[k] = fmaxf(0.f, s);
        }
        float o0 = b3[0], o1 = b3[1];
        #pragma unroll
        for (int j = 0; j < 8; ++j) { o0 += w3[j] * z2[j]; o1 += w3[8 + j] * z2[j]; }

        *(float2*)(out + (size_t)b * 2) = make_float2(o0, o1);   // coalesced 8B store
    }
}

extern "C" void kernel_launch(void* const* d_in, const int* in_sizes, int n_in,
                              void* d_out, int out_size, void* d_ws, size_t ws_size,
                              hipStream_t stream) {
    const float* nf  = (const float*)d_in[0];
    const float* adj = (const float*)d_in[1];
    const float* pw  = (const float*)d_in[2];
    const float* pb  = (const float*)d_in[3];
    const float* w1  = (const float*)d_in[4];
    const float* b1  = (const float*)d_in[5];
    const float* w2  = (const float*)d_in[6];
    const float* b2  = (const float*)d_in[7];
    const float* w3  = (const float*)d_in[8];
    const float* b3  = (const float*)d_in[9];
    float* out = (float*)d_out;

    const int B = in_sizes[0] / NNODE;          // 131072
    const int grid = (B + TILE - 1) / TILE;     // 2115 blocks
    const size_t ldsBytes = (size_t)TILE * STRIDE * sizeof(float);  // 80,848 B (>64K: needs attr)

    hipFuncSetAttribute(reinterpret_cast<const void*>(gcnn_fused),
                        hipFuncAttributeMaxDynamicSharedMemorySize, (int)ldsBytes);

    gcnn_fused<<<grid, 64, ldsBytes, stream>>>(nf, adj, pw, pb, w1, b1, w2, b2, w3, b3, out, B);
}